// Round 10
// baseline (17.896 us; speedup 1.0000x reference)
//
#include <hip/hip_runtime.h>
#include <math.h>

#define NG    512
#define IMG_W 256
#define IMG_H 192

#define NEAR_P    0.1f
#define FAR_P     100.0f
#define ALPHA_MAX 0.99f

#define PIX     64     // pixels per block (one row strip)
#define CHUNKS  4
#define TPB     256    // PIX * CHUNKS

#define CULL_K  4.0f   // cull extent in sigmas (dropped terms <= op*e^-8)

// Single fused dispatch, 768 blocks (one 64x1 strip each):
//  P0  coalesced float4 staging of pos/scl into LDS (aliased region)
//  P1+P2 (registers): each thread preprocesses cheaply its 2 gaussians
//      (g=tid, g=tid+256), strip pre-culls with the conservative bound
//      rb = K*sqrt(smax^2 * lmax(JJ^T)), then 8-segment order-preserving
//      ballot compaction -> s_list (ascending id) + u32 monotonic keys
//  P4  full preprocess of pre-survivors (two half-passes, M may be >TPB),
//      exact ellipse-bbox cull; culled entries set key sentinel 0xFFFFFFFF
//  P3  rank among exact survivors = #{j: kj<kt || (kj==kt && j<t)},
//      uint4 LDS reads; scatter records into depth order
//  P5  4-way transmittance-split composite, sequential record reads

union SB {
    struct { float pos[NG*3]; float scl[NG*3]; } st;            // 12 KB
    struct { float4 rec1[NG]; float4 part[CHUNKS][PIX]; } cp;   // 12 KB
};

__global__ __launch_bounds__(TPB) void gs_fused(
    const float* __restrict__ pos,
    const float* __restrict__ scl,
    const float* __restrict__ rot,
    const float* __restrict__ opa,
    const float* __restrict__ col,
    const float* __restrict__ vm,
    const int*   __restrict__ fov,
    const float* __restrict__ bg,
    float* __restrict__ out)
{
    __shared__ SB sb;                           // 12 KB (time-multiplexed)
    __shared__ float4 s_rec0[NG];               // 8 KB (scatter target)
    __shared__ float  s_bcol[NG];               // 2 KB
    __shared__ __align__(16) unsigned s_ku[NG + 4];  // 2 KB (+pads)
    __shared__ unsigned short s_list[NG];       // 1 KB
    __shared__ int    s_wtot[8], s_Mf;
    __shared__ float  s_out[PIX*3];

    const int tid  = threadIdx.x;
    const int lane = tid & 63;
    const int wv   = tid >> 6;
    const int b    = blockIdx.x;
    const float yf  = (float)(b >> 2);
    const float x0f = (float)((b & 3) * PIX);

    const float fx = (float)IMG_W /
        (2.0f * __tanf((float)fov[0] * (float)(M_PI / 180.0) * 0.5f));

    const float W00 = vm[0],  W01 = vm[1],  W02 = vm[2],  t0 = vm[3];
    const float W10 = vm[4],  W11 = vm[5],  W12 = vm[6],  t1 = vm[7];
    const float W20 = vm[8],  W21 = vm[9],  W22 = vm[10], t2 = vm[11];

    // ---------------- P0: coalesced staging of pos/scl --------------------
    {
        const float4* p4 = (const float4*)pos;
        const float4* s4 = (const float4*)scl;
        float4* dp = (float4*)sb.st.pos;
        float4* ds = (float4*)sb.st.scl;
        if (tid < (NG*3)/4) dp[tid] = p4[tid];                 // 384
        int j = tid - (NG*3)/4;
        if (j >= 0) ds[j] = s4[j];                             // 128 (wait, TPB-384<0? 256-384) 
        // TPB==256 < 384: cover remaining pos + all scl below
        int i2 = tid + TPB;
        if (i2 < (NG*3)/4) dp[i2] = p4[i2];                    // pos[256..383]
        for (int i = tid; i < (NG*3)/4; i += TPB) ds[i] = s4[i];
    }
    __syncthreads();                                             // B0

    // -------- P1+P2: cheap pass + pre-cull in registers (2/thread) --------
    bool  pr[2];
    unsigned key32[2];
    #pragma unroll
    for (int gg = 0; gg < 2; ++gg) {
        const int g = tid + gg * TPB;
        float px = sb.st.pos[g*3+0], py = sb.st.pos[g*3+1], pz = sb.st.pos[g*3+2];
        float X = W00*px + W01*py + W02*pz + t0;
        float Y = W10*px + W11*py + W12*pz + t1;
        float Z = W20*px + W21*py + W22*pz + t2;

        float zs = fmaxf(Z, NEAR_P);
        float rz = __fdividef(1.0f, zs);
        float fxrz = fx * rz;

        float mx = fxrz * X + (float)IMG_W * 0.5f;
        float my = (float)IMG_H * 0.5f - fxrz * Y;

        float s0 = sb.st.scl[g*3+0], s1 = sb.st.scl[g*3+1], s2 = sb.st.scl[g*3+2];
        float smax2 = fmaxf(fmaxf(s0*s0, s1*s1), s2*s2);   // = lmax(cov3d)
        float Xr = X * rz, Yr = Y * rz;
        float J2 = fxrz*fxrz * (1.0f + Xr*Xr + Yr*Yr);     // = lmax(J J^T)
        float rb = CULL_K * sqrtf(smax2 * J2 + 1e-5f);

        bool visible = (Z > NEAR_P) && (Z < FAR_P);
        pr[gg] = visible &
                 (fabsf(my - yf) <= rb) &
                 (mx >= x0f - rb) & (mx <= x0f + 63.0f + rb);

        unsigned u = __float_as_uint(-Z);
        key32[gg] = (u & 0x80000000u) ? ~u : (u | 0x80000000u);
    }

    unsigned long long m0 = __ballot(pr[0]);
    unsigned long long m1 = __ballot(pr[1]);
    unsigned long long lt = (1ull << lane) - 1ull;
    if (lane == 0) {
        s_wtot[wv]     = __popcll(m0);
        s_wtot[4 + wv] = __popcll(m1);
        if (tid == 0) s_Mf = 0;
    }
    __syncthreads();                                             // B1

    int w8[8];
    #pragma unroll
    for (int i = 0; i < 8; ++i) w8[i] = s_wtot[i];
    int pref0 = 0, pref1 = 0, M = 0;
    #pragma unroll
    for (int i = 0; i < 8; ++i) {
        if (i < wv)     pref0 += w8[i];
        if (i < 4 + wv) pref1 += w8[i];
        M += w8[i];
    }

    if (pr[0]) {
        int p = pref0 + __popcll(m0 & lt);
        s_list[p] = (unsigned short)tid;
        s_ku[p]   = key32[0];
    }
    if (pr[1]) {
        int p = pref1 + __popcll(m1 & lt);
        s_list[p] = (unsigned short)(tid + TPB);
        s_ku[p]   = key32[1];
    }
    if (tid < 4) s_ku[M + tid] = 0xFFFFFFFFu;    // pads for uint4 rank loop
    __syncthreads();                                             // B2

    // ------- P4: full preprocess + exact bbox cull (two half-passes) ------
    bool   qpA[2]   = {false, false};
    float4 rec0A[2], rec1A[2];
    float  bcolA[2] = {0.0f, 0.0f};
    unsigned ktA[2] = {0, 0};

    #pragma unroll
    for (int half = 0; half < 2; ++half) {
        if (half == 1 && M <= TPB) continue;     // block-uniform
        const int t = half * TPB + tid;
        bool qp = false;
        if (t < M) {
            const int g = s_list[t];
            ktA[half] = s_ku[t];

            float4 q4 = ((const float4*)rot)[g];
            float qw = q4.x, qx = q4.y, qy = q4.z, qz = q4.w;
            float rn = __frsqrt_rn(qw*qw + qx*qx + qy*qy + qz*qz);
            qw *= rn; qx *= rn; qy *= rn; qz *= rn;
            float R00 = 1.f - 2.f*(qy*qy + qz*qz);
            float R01 = 2.f*(qx*qy - qw*qz);
            float R02 = 2.f*(qx*qz + qw*qy);
            float R10 = 2.f*(qx*qy + qw*qz);
            float R11 = 1.f - 2.f*(qx*qx + qz*qz);
            float R12 = 2.f*(qy*qz - qw*qx);
            float R20 = 2.f*(qx*qz - qw*qy);
            float R21 = 2.f*(qy*qz + qw*qx);
            float R22 = 1.f - 2.f*(qx*qx + qy*qy);

            float s0 = sb.st.scl[g*3+0], s1 = sb.st.scl[g*3+1], s2 = sb.st.scl[g*3+2];
            float q0 = s0*s0, q1 = s1*s1, q2 = s2*s2;
            float C00 = R00*R00*q0 + R01*R01*q1 + R02*R02*q2;
            float C01 = R00*R10*q0 + R01*R11*q1 + R02*R12*q2;
            float C02 = R00*R20*q0 + R01*R21*q1 + R02*R22*q2;
            float C11 = R10*R10*q0 + R11*R11*q1 + R12*R12*q2;
            float C12 = R10*R20*q0 + R11*R21*q1 + R12*R22*q2;
            float C22 = R20*R20*q0 + R21*R21*q1 + R22*R22*q2;

            float px = sb.st.pos[g*3+0], py = sb.st.pos[g*3+1], pz = sb.st.pos[g*3+2];
            float X = W00*px + W01*py + W02*pz + t0;
            float Y = W10*px + W11*py + W12*pz + t1;
            float Z = W20*px + W21*py + W22*pz + t2;

            float zs = fmaxf(Z, NEAR_P);
            float rz = __fdividef(1.0f, zs);
            float fxrz = fx * rz;

            float mx = fxrz * X + (float)IMG_W * 0.5f;
            float my = (float)IMG_H * 0.5f - fxrz * Y;

            float j02 = -fxrz * X * rz;
            float j12 = -fxrz * Y * rz;
            float T00 = fxrz*W00 + j02*W20;
            float T01 = fxrz*W01 + j02*W21;
            float T02 = fxrz*W02 + j02*W22;
            float T10 = fxrz*W10 + j12*W20;
            float T11 = fxrz*W11 + j12*W21;
            float T12 = fxrz*W12 + j12*W22;

            float u0 = C00*T00 + C01*T01 + C02*T02;
            float u1 = C01*T00 + C11*T01 + C12*T02;
            float u2 = C02*T00 + C12*T01 + C22*T02;
            float v0 = C00*T10 + C01*T11 + C02*T12;
            float v1 = C01*T10 + C11*T11 + C12*T12;
            float v2 = C02*T10 + C12*T11 + C22*T12;
            float a    = T00*u0 + T01*u1 + T02*u2;
            float bcov = 0.5f * ((T00*v0 + T01*v1 + T02*v2) + (T10*u0 + T11*u1 + T12*u2));
            float c    = T10*v0 + T11*v1 + T12*v2;

            float mean_e = 0.5f * (a + c);
            float disc = sqrtf(fmaxf(0.25f*(a - c)*(a - c) + bcov*bcov, 0.0f));
            float min_eig = mean_e - disc;
            float eps = (min_eig <= 0.0f) ? (fabsf(min_eig) + 1e-6f) : 0.0f;
            a += eps; c += eps;

            float det  = fmaxf(a*c - bcov*bcov, 1e-12f);
            float rdet = __fdividef(1.0f, det);
            float ca = c * rdet, cbv = -bcov * rdet, cc = a * rdet;
            float op = __fdividef(1.0f, 1.0f + __expf(-opa[g]));

            // exact ellipse bbox half-extents at K sigmas
            float ex = CULL_K * sqrtf(a);
            float ey = CULL_K * sqrtf(c);
            qp = (fabsf(my - yf) <= ey) &
                 (mx >= x0f - ex) & (mx <= x0f + 63.0f + ex);

            rec0A[half] = make_float4(-0.5f*ca, -cbv, -0.5f*cc, mx);
            rec1A[half] = make_float4(my, op, col[g*3+0], col[g*3+1]);
            bcolA[half] = col[g*3+2];

            if (!qp) s_ku[t] = 0xFFFFFFFFu;   // excluded from ranks
        }
        unsigned long long mq = __ballot(qp);
        if (lane == 0) atomicAdd(&s_Mf, __popcll(mq));
        qpA[half] = qp;
    }
    __syncthreads();                                             // B3

    // ------- P3: rank among exact survivors + depth-ordered scatter -------
    #pragma unroll
    for (int half = 0; half < 2; ++half) {
        if (half == 1 && M <= TPB) continue;
        const int t = half * TPB + tid;
        if (t < M && qpA[half]) {
            const unsigned kt = ktA[half];
            const uint4* ku4 = (const uint4*)s_ku;
            int r = 0;
            const int M4 = (M + 3) >> 2;
            for (int j4 = 0; j4 < M4; ++j4) {
                uint4 kv = ku4[j4];
                int j = 4*j4;
                r += (int)((kv.x < kt) | ((kv.x == kt) & (j     < t)));
                r += (int)((kv.y < kt) | ((kv.y == kt) & (j + 1 < t)));
                r += (int)((kv.z < kt) | ((kv.z == kt) & (j + 2 < t)));
                r += (int)((kv.w < kt) | ((kv.w == kt) & (j + 3 < t)));
            }
            s_rec0[r]       = rec0A[half];
            sb.cp.rec1[r]   = rec1A[half];
            s_bcol[r]       = bcolA[half];
        }
    }
    __syncthreads();                                             // B4

    // ---------------- P5: chunked composite -------------------------------
    const int Mf = s_Mf;
    const int qn = (Mf + CHUNKS - 1) / CHUNKS;
    const int lpix  = tid & 63;
    const int chunk = tid >> 6;
    int start = chunk * qn; if (start > Mf) start = Mf;
    int end   = start + qn; if (end > Mf) end = Mf;

    const float fxp = x0f + (float)lpix;

    float Tr = 1.0f, ar = 0.0f, ag = 0.0f, abv = 0.0f;
    for (int i = start; i < end; ++i) {
        float4 r0 = s_rec0[i];
        float4 r1 = sb.cp.rec1[i];
        float  bc = s_bcol[i];
        float dx = fxp - r0.w;
        float dy = yf  - r1.x;
        float qv = (r0.x*dx)*dx + (r0.y*dx)*dy + (r0.z*dy)*dy;  // = -0.5*q
        float G = __expf(fminf(qv, 0.0f));
        float alpha = fminf(r1.y * G, ALPHA_MAX);
        float wgt = alpha * Tr;
        ar  += wgt * r1.z;
        ag  += wgt * r1.w;
        abv += wgt * bc;
        Tr  *= (1.0f - alpha);
    }
    sb.cp.part[chunk][lpix] = make_float4(ar, ag, abv, Tr);
    __syncthreads();                                             // B5

    if (chunk == 0) {
        float4 c0 = sb.cp.part[0][lpix], c1 = sb.cp.part[1][lpix];
        float4 c2 = sb.cp.part[2][lpix], c3 = sb.cp.part[3][lpix];
        float T0 = c0.w, T01 = T0*c1.w, T012 = T01*c2.w, Tall = T012*c3.w;
        float r  = c0.x + T0*c1.x + T01*c2.x + T012*c3.x;
        float gc = c0.y + T0*c1.y + T01*c2.y + T012*c3.y;
        float bb = c0.z + T0*c1.z + T01*c2.z + T012*c3.z;
        s_out[3*lpix+0] = r  + Tall * bg[0];
        s_out[3*lpix+1] = gc + Tall * bg[1];
        s_out[3*lpix+2] = bb + Tall * bg[2];
    }
    __syncthreads();                                             // B6
    if (tid < PIX*3)
        out[b * (PIX*3) + tid] = s_out[tid];
}

extern "C" void kernel_launch(void* const* d_in, const int* in_sizes, int n_in,
                              void* d_out, int out_size, void* d_ws, size_t ws_size,
                              hipStream_t stream) {
    const float* pos = (const float*)d_in[0];
    const float* scl = (const float*)d_in[1];
    const float* rot = (const float*)d_in[2];
    const float* opa = (const float*)d_in[3];
    const float* col = (const float*)d_in[4];
    const float* vm  = (const float*)d_in[5];
    const float* bgp = (const float*)d_in[6];
    const int*   fov = (const int*)d_in[7];

    float* out = (float*)d_out;

    gs_fused<<<(IMG_H * IMG_W) / PIX, TPB, 0, stream>>>(
        pos, scl, rot, opa, col, vm, fov, bgp, out);
}

// Round 11
// 17.559 us; speedup vs baseline: 1.0192x; 1.0192x over previous
//
#include <hip/hip_runtime.h>
#include <math.h>

#define NG    512
#define IMG_W 256
#define IMG_H 192

#define NEAR_P    0.1f
#define FAR_P     100.0f
#define ALPHA_MAX 0.99f

#define PIX     64     // pixels per block (one row strip)
#define CHUNKS  4
#define TPB     256    // PIX * CHUNKS

#define CULL_K  4.0f   // cull extent in sigmas (dropped terms <= op*e^-8)

// Single fused dispatch, 768 blocks (one 64x1 strip each). 6 barriers.
//  P1+P2 (registers, global reads): thread cheap-preprocesses gaussians
//      g=tid and g=tid+256, strip pre-culls with the conservative bound
//      rb = K*sqrt(smax^2 * lmax(JJ^T)); 8-segment order-preserving ballot
//      compaction -> s_list (ascending id) + u32 monotonic depth keys
//  P4  full preprocess of pre-survivors (two half-passes, M may be >TPB),
//      exact ellipse-bbox cull; culled entries set key sentinel 0xFFFFFFFF
//      (visible keys are < 0x80000000, so the sentinel is safe)
//  P3  rank among exact survivors = #{j: kj<kt || (kj==kt && j<t)},
//      uint4 LDS reads; scatter records into depth order
//  P5  4-way transmittance-split composite, sequential record reads

__global__ __launch_bounds__(TPB) void gs_fused(
    const float* __restrict__ pos,
    const float* __restrict__ scl,
    const float* __restrict__ rot,
    const float* __restrict__ opa,
    const float* __restrict__ col,
    const float* __restrict__ vm,
    const int*   __restrict__ fov,
    const float* __restrict__ bg,
    float* __restrict__ out)
{
    __shared__ float4 s_rec0[NG];               // 8 KB (depth-ordered A,B,C,mx)
    __shared__ float4 s_rec1[NG];               // 8 KB (my, op, col_r, col_g)
    __shared__ float  s_bcol[NG];               // 2 KB
    __shared__ __align__(16) unsigned s_ku[NG + 4];  // 2 KB (+pads)
    __shared__ unsigned short s_list[NG];       // 1 KB
    __shared__ int    s_wtot[8], s_Mf;
    __shared__ float4 s_part[CHUNKS][PIX];      // 4 KB
    __shared__ float  s_out[PIX*3];

    const int tid  = threadIdx.x;
    const int lane = tid & 63;
    const int wv   = tid >> 6;
    const int b    = blockIdx.x;
    const float yf  = (float)(b >> 2);
    const float x0f = (float)((b & 3) * PIX);

    const float fx = (float)IMG_W /
        (2.0f * __tanf((float)fov[0] * (float)(M_PI / 180.0) * 0.5f));

    const float W00 = vm[0],  W01 = vm[1],  W02 = vm[2],  t0 = vm[3];
    const float W10 = vm[4],  W11 = vm[5],  W12 = vm[6],  t1 = vm[7];
    const float W20 = vm[8],  W21 = vm[9],  W22 = vm[10], t2 = vm[11];

    // -------- P1+P2: cheap pass + pre-cull in registers (2/thread) --------
    bool     pr[2];
    unsigned key32[2];
    #pragma unroll
    for (int gg = 0; gg < 2; ++gg) {
        const int g = tid + gg * TPB;
        float px = pos[g*3+0], py = pos[g*3+1], pz = pos[g*3+2];
        float X = W00*px + W01*py + W02*pz + t0;
        float Y = W10*px + W11*py + W12*pz + t1;
        float Z = W20*px + W21*py + W22*pz + t2;

        float zs = fmaxf(Z, NEAR_P);
        float rz = __fdividef(1.0f, zs);
        float fxrz = fx * rz;

        float mx = fxrz * X + (float)IMG_W * 0.5f;
        float my = (float)IMG_H * 0.5f - fxrz * Y;

        float s0 = scl[g*3+0], s1 = scl[g*3+1], s2 = scl[g*3+2];
        float smax2 = fmaxf(fmaxf(s0*s0, s1*s1), s2*s2);   // = lmax(cov3d)
        float Xr = X * rz, Yr = Y * rz;
        float J2 = fxrz*fxrz * (1.0f + Xr*Xr + Yr*Yr);     // = lmax(J J^T)
        float rb = CULL_K * sqrtf(smax2 * J2 + 1e-5f);

        bool visible = (Z > NEAR_P) && (Z < FAR_P);
        pr[gg] = visible &
                 (fabsf(my - yf) <= rb) &
                 (mx >= x0f - rb) & (mx <= x0f + 63.0f + rb);

        unsigned u = __float_as_uint(-Z);
        key32[gg] = (u & 0x80000000u) ? ~u : (u | 0x80000000u);
    }

    unsigned long long m0 = __ballot(pr[0]);
    unsigned long long m1 = __ballot(pr[1]);
    unsigned long long lt = (1ull << lane) - 1ull;
    if (lane == 0) {
        s_wtot[wv]     = __popcll(m0);
        s_wtot[4 + wv] = __popcll(m1);
        if (tid == 0) s_Mf = 0;
    }
    __syncthreads();                                             // B1

    int w8[8];
    #pragma unroll
    for (int i = 0; i < 8; ++i) w8[i] = s_wtot[i];
    int pref0 = 0, pref1 = 0, M = 0;
    #pragma unroll
    for (int i = 0; i < 8; ++i) {
        if (i < wv)     pref0 += w8[i];
        if (i < 4 + wv) pref1 += w8[i];
        M += w8[i];
    }

    if (pr[0]) {
        int p = pref0 + __popcll(m0 & lt);
        s_list[p] = (unsigned short)tid;
        s_ku[p]   = key32[0];
    }
    if (pr[1]) {
        int p = pref1 + __popcll(m1 & lt);
        s_list[p] = (unsigned short)(tid + TPB);
        s_ku[p]   = key32[1];
    }
    if (tid < 4) s_ku[M + tid] = 0xFFFFFFFFu;    // pads for uint4 rank loop
    __syncthreads();                                             // B2

    // ------- P4: full preprocess + exact bbox cull (two half-passes) ------
    bool     qpA[2]   = {false, false};
    float4   rec0A[2], rec1A[2];
    float    bcolA[2] = {0.0f, 0.0f};
    unsigned ktA[2]   = {0, 0};

    #pragma unroll
    for (int half = 0; half < 2; ++half) {
        if (half == 1 && M <= TPB) continue;     // block-uniform
        const int t = half * TPB + tid;
        bool qp = false;
        if (t < M) {
            const int g = s_list[t];
            ktA[half] = s_ku[t];

            float4 q4 = ((const float4*)rot)[g];
            float qw = q4.x, qx = q4.y, qy = q4.z, qz = q4.w;
            float rn = __frsqrt_rn(qw*qw + qx*qx + qy*qy + qz*qz);
            qw *= rn; qx *= rn; qy *= rn; qz *= rn;
            float R00 = 1.f - 2.f*(qy*qy + qz*qz);
            float R01 = 2.f*(qx*qy - qw*qz);
            float R02 = 2.f*(qx*qz + qw*qy);
            float R10 = 2.f*(qx*qy + qw*qz);
            float R11 = 1.f - 2.f*(qx*qx + qz*qz);
            float R12 = 2.f*(qy*qz - qw*qx);
            float R20 = 2.f*(qx*qz - qw*qy);
            float R21 = 2.f*(qy*qz + qw*qx);
            float R22 = 1.f - 2.f*(qx*qx + qy*qy);

            float s0 = scl[g*3+0], s1 = scl[g*3+1], s2 = scl[g*3+2];
            float q0 = s0*s0, q1 = s1*s1, q2 = s2*s2;
            float C00 = R00*R00*q0 + R01*R01*q1 + R02*R02*q2;
            float C01 = R00*R10*q0 + R01*R11*q1 + R02*R12*q2;
            float C02 = R00*R20*q0 + R01*R21*q1 + R02*R22*q2;
            float C11 = R10*R10*q0 + R11*R11*q1 + R12*R12*q2;
            float C12 = R10*R20*q0 + R11*R21*q1 + R12*R22*q2;
            float C22 = R20*R20*q0 + R21*R21*q1 + R22*R22*q2;

            float px = pos[g*3+0], py = pos[g*3+1], pz = pos[g*3+2];
            float X = W00*px + W01*py + W02*pz + t0;
            float Y = W10*px + W11*py + W12*pz + t1;
            float Z = W20*px + W21*py + W22*pz + t2;

            float zs = fmaxf(Z, NEAR_P);
            float rz = __fdividef(1.0f, zs);
            float fxrz = fx * rz;

            float mx = fxrz * X + (float)IMG_W * 0.5f;
            float my = (float)IMG_H * 0.5f - fxrz * Y;

            float j02 = -fxrz * X * rz;
            float j12 = -fxrz * Y * rz;
            float T00 = fxrz*W00 + j02*W20;
            float T01 = fxrz*W01 + j02*W21;
            float T02 = fxrz*W02 + j02*W22;
            float T10 = fxrz*W10 + j12*W20;
            float T11 = fxrz*W11 + j12*W21;
            float T12 = fxrz*W12 + j12*W22;

            float u0 = C00*T00 + C01*T01 + C02*T02;
            float u1 = C01*T00 + C11*T01 + C12*T02;
            float u2 = C02*T00 + C12*T01 + C22*T02;
            float v0 = C00*T10 + C01*T11 + C02*T12;
            float v1 = C01*T10 + C11*T11 + C12*T12;
            float v2 = C02*T10 + C12*T11 + C22*T12;
            float a    = T00*u0 + T01*u1 + T02*u2;
            float bcov = 0.5f * ((T00*v0 + T01*v1 + T02*v2) + (T10*u0 + T11*u1 + T12*u2));
            float c    = T10*v0 + T11*v1 + T12*v2;

            float mean_e = 0.5f * (a + c);
            float disc = sqrtf(fmaxf(0.25f*(a - c)*(a - c) + bcov*bcov, 0.0f));
            float min_eig = mean_e - disc;
            float eps = (min_eig <= 0.0f) ? (fabsf(min_eig) + 1e-6f) : 0.0f;
            a += eps; c += eps;

            float det  = fmaxf(a*c - bcov*bcov, 1e-12f);
            float rdet = __fdividef(1.0f, det);
            float ca = c * rdet, cbv = -bcov * rdet, cc = a * rdet;
            float op = __fdividef(1.0f, 1.0f + __expf(-opa[g]));

            // exact ellipse bbox half-extents at K sigmas
            float ex = CULL_K * sqrtf(a);
            float ey = CULL_K * sqrtf(c);
            qp = (fabsf(my - yf) <= ey) &
                 (mx >= x0f - ex) & (mx <= x0f + 63.0f + ex);

            rec0A[half] = make_float4(-0.5f*ca, -cbv, -0.5f*cc, mx);
            rec1A[half] = make_float4(my, op, col[g*3+0], col[g*3+1]);
            bcolA[half] = col[g*3+2];

            if (!qp) s_ku[t] = 0xFFFFFFFFu;   // excluded from ranks
        }
        unsigned long long mq = __ballot(qp);
        if (lane == 0) atomicAdd(&s_Mf, __popcll(mq));
        qpA[half] = qp;
    }
    __syncthreads();                                             // B3

    // ------- P3: rank among exact survivors + depth-ordered scatter -------
    #pragma unroll
    for (int half = 0; half < 2; ++half) {
        if (half == 1 && M <= TPB) continue;
        const int t = half * TPB + tid;
        if (t < M && qpA[half]) {
            const unsigned kt = ktA[half];
            const uint4* ku4 = (const uint4*)s_ku;
            int r = 0;
            const int M4 = (M + 3) >> 2;
            for (int j4 = 0; j4 < M4; ++j4) {
                uint4 kv = ku4[j4];
                int j = 4*j4;
                r += (int)((kv.x < kt) | ((kv.x == kt) & (j     < t)));
                r += (int)((kv.y < kt) | ((kv.y == kt) & (j + 1 < t)));
                r += (int)((kv.z < kt) | ((kv.z == kt) & (j + 2 < t)));
                r += (int)((kv.w < kt) | ((kv.w == kt) & (j + 3 < t)));
            }
            s_rec0[r] = rec0A[half];
            s_rec1[r] = rec1A[half];
            s_bcol[r] = bcolA[half];
        }
    }
    __syncthreads();                                             // B4

    // ---------------- P5: chunked composite -------------------------------
    const int Mf = s_Mf;
    const int qn = (Mf + CHUNKS - 1) / CHUNKS;
    const int lpix  = tid & 63;
    const int chunk = tid >> 6;
    int start = chunk * qn; if (start > Mf) start = Mf;
    int end   = start + qn; if (end > Mf) end = Mf;

    const float fxp = x0f + (float)lpix;

    float Tr = 1.0f, ar = 0.0f, ag = 0.0f, abv = 0.0f;
    for (int i = start; i < end; ++i) {
        float4 r0 = s_rec0[i];
        float4 r1 = s_rec1[i];
        float  bc = s_bcol[i];
        float dx = fxp - r0.w;
        float dy = yf  - r1.x;
        float qv = (r0.x*dx)*dx + (r0.y*dx)*dy + (r0.z*dy)*dy;  // = -0.5*q
        float G = __expf(fminf(qv, 0.0f));
        float alpha = fminf(r1.y * G, ALPHA_MAX);
        float wgt = alpha * Tr;
        ar  += wgt * r1.z;
        ag  += wgt * r1.w;
        abv += wgt * bc;
        Tr  *= (1.0f - alpha);
    }
    s_part[chunk][lpix] = make_float4(ar, ag, abv, Tr);
    __syncthreads();                                             // B5

    if (chunk == 0) {
        float4 c0 = s_part[0][lpix], c1 = s_part[1][lpix];
        float4 c2 = s_part[2][lpix], c3 = s_part[3][lpix];
        float T0 = c0.w, T01 = T0*c1.w, T012 = T01*c2.w, Tall = T012*c3.w;
        float r  = c0.x + T0*c1.x + T01*c2.x + T012*c3.x;
        float gc = c0.y + T0*c1.y + T01*c2.y + T012*c3.y;
        float bb = c0.z + T0*c1.z + T01*c2.z + T012*c3.z;
        s_out[3*lpix+0] = r  + Tall * bg[0];
        s_out[3*lpix+1] = gc + Tall * bg[1];
        s_out[3*lpix+2] = bb + Tall * bg[2];
    }
    __syncthreads();                                             // B6
    if (tid < PIX*3)
        out[b * (PIX*3) + tid] = s_out[tid];
}

extern "C" void kernel_launch(void* const* d_in, const int* in_sizes, int n_in,
                              void* d_out, int out_size, void* d_ws, size_t ws_size,
                              hipStream_t stream) {
    const float* pos = (const float*)d_in[0];
    const float* scl = (const float*)d_in[1];
    const float* rot = (const float*)d_in[2];
    const float* opa = (const float*)d_in[3];
    const float* col = (const float*)d_in[4];
    const float* vm  = (const float*)d_in[5];
    const float* bgp = (const float*)d_in[6];
    const int*   fov = (const int*)d_in[7];

    float* out = (float*)d_out;

    gs_fused<<<(IMG_H * IMG_W) / PIX, TPB, 0, stream>>>(
        pos, scl, rot, opa, col, vm, fov, bgp, out);
}

// Round 12
// 14.733 us; speedup vs baseline: 1.2147x; 1.1918x over previous
//
#include <hip/hip_runtime.h>
#include <math.h>

#define NG    512
#define IMG_W 256
#define IMG_H 192

#define NEAR_P    0.1f
#define FAR_P     100.0f
#define ALPHA_MAX 0.99f

#define PIX     64     // pixels per block (one row strip)
#define CHUNKS  4
#define TPB     256    // PIX * CHUNKS

#define CULL_K  4.0f   // cull extent in sigmas (dropped terms <= op*e^-8)

// R9 structure (known best, 14.8 us) + direct epilogue store.
//  P1  cheap pass, all NG: depth, mx/my, conservative radius bound
//  P2  strip pre-cull + order-preserving ballot compaction -> s_list/s_ku
//      (u64 key = monotonic(-depth)<<16 | id == reference stable argsort)
//  P4  full preprocess of pre-survivors (two half-passes), exact
//      ellipse-bbox cull; culled keys set to ~0 sentinel
//  P3  rank among exact survivors (ulonglong2 LDS reads), depth scatter
//  P5  4-way transmittance-split composite; chunk-0 combines and stores
//      final RGB directly (no s_out round-trip)

__global__ __launch_bounds__(TPB) void gs_fused(
    const float* __restrict__ pos,
    const float* __restrict__ scl,
    const float* __restrict__ rot,
    const float* __restrict__ opa,
    const float* __restrict__ col,
    const float* __restrict__ vm,
    const int*   __restrict__ fov,
    const float* __restrict__ bg,
    float* __restrict__ out)
{
    __shared__ float4 s_cr0[NG];     // P1-P2: {mx, my|1e30, rb|0, keyf}; later rec0
    __shared__ float4 s_rec1[NG];    // {my, op, col_r, col_g}
    __shared__ float  s_bcol[NG];    // col_b
    __shared__ __align__(16) unsigned long long s_ku[NG + 2];
    __shared__ unsigned short s_list[NG];
    __shared__ int    s_wtot[4], s_woff[4], s_M, s_Mf;
    __shared__ float4 s_part[CHUNKS][PIX];

    const int tid  = threadIdx.x;
    const int lane = tid & 63;
    const int wv   = tid >> 6;
    const int b    = blockIdx.x;
    const float yf  = (float)(b >> 2);
    const float x0f = (float)((b & 3) * PIX);

    const float fx = (float)IMG_W /
        (2.0f * __tanf((float)fov[0] * (float)(M_PI / 180.0) * 0.5f));

    const float W00 = vm[0],  W01 = vm[1],  W02 = vm[2],  t0 = vm[3];
    const float W10 = vm[4],  W11 = vm[5],  W12 = vm[6],  t1 = vm[7];
    const float W20 = vm[8],  W21 = vm[9],  W22 = vm[10], t2 = vm[11];

    // ---------------- P1: cheap pass (2 gaussians/thread) -----------------
    #pragma unroll
    for (int gg = 0; gg < 2; ++gg) {
        const int g = tid + gg * TPB;
        float px = pos[g*3+0], py = pos[g*3+1], pz = pos[g*3+2];
        float X = W00*px + W01*py + W02*pz + t0;
        float Y = W10*px + W11*py + W12*pz + t1;
        float Z = W20*px + W21*py + W22*pz + t2;

        float zs = fmaxf(Z, NEAR_P);
        float rz = __fdividef(1.0f, zs);
        float fxrz = fx * rz;

        float mx = fxrz * X + (float)IMG_W * 0.5f;
        float my = (float)IMG_H * 0.5f - fxrz * Y;

        float s0 = scl[g*3+0], s1 = scl[g*3+1], s2 = scl[g*3+2];
        float smax2 = fmaxf(fmaxf(s0*s0, s1*s1), s2*s2);   // = lmax(cov3d)
        float Xr = X * rz, Yr = Y * rz;
        float J2 = fxrz*fxrz * (1.0f + Xr*Xr + Yr*Yr);     // = lmax(J J^T)
        float rb = CULL_K * sqrtf(smax2 * J2 + 1e-5f);

        bool visible = (Z > NEAR_P) && (Z < FAR_P);
        s_cr0[g] = make_float4(mx,
                               visible ? my : 1e30f,
                               visible ? rb : 0.0f,
                               visible ? -Z : INFINITY);
    }
    __syncthreads();                                             // B1

    // ---------------- P2: pre-cull + ballot compaction --------------------
    const int g0 = 2*tid, g1 = g0 + 1;
    float4 cr0 = s_cr0[g0];
    float4 cr1 = s_cr0[g1];
    bool p0 = (fabsf(cr0.y - yf) <= cr0.z) &
              (cr0.x >= x0f - cr0.z) & (cr0.x <= x0f + 63.0f + cr0.z);
    bool p1 = (fabsf(cr1.y - yf) <= cr1.z) &
              (cr1.x >= x0f - cr1.z) & (cr1.x <= x0f + 63.0f + cr1.z);

    unsigned long long m0 = __ballot(p0);
    unsigned long long m1 = __ballot(p1);
    unsigned long long lt = (1ull << lane) - 1ull;

    if (lane == 0) s_wtot[wv] = __popcll(m0) + __popcll(m1);
    __syncthreads();                                             // B2
    if (tid == 0) {
        int acc = 0;
        for (int i = 0; i < 4; ++i) { s_woff[i] = acc; acc += s_wtot[i]; }
        s_M = acc;
        s_Mf = 0;
        s_ku[acc]     = ~0ull;   // pad for ulonglong2 rank loop
        s_ku[acc + 1] = ~0ull;
    }
    __syncthreads();                                             // B3
    int basep = s_woff[wv] + __popcll(m0 & lt) + __popcll(m1 & lt);
    if (p0) {
        unsigned u = __float_as_uint(cr0.w);
        unsigned mm = (u & 0x80000000u) ? ~u : (u | 0x80000000u);
        s_list[basep] = (unsigned short)g0;
        s_ku[basep] = (((unsigned long long)mm) << 16) | (unsigned)g0;
    }
    if (p1) {
        int p = basep + (p0 ? 1 : 0);
        unsigned u = __float_as_uint(cr1.w);
        unsigned mm = (u & 0x80000000u) ? ~u : (u | 0x80000000u);
        s_list[p] = (unsigned short)g1;
        s_ku[p] = (((unsigned long long)mm) << 16) | (unsigned)g1;
    }
    __syncthreads();                                             // B4

    const int M = s_M;

    // ------- P4: full preprocess + exact bbox cull (two half-passes) ------
    bool   qpA[2]   = {false, false};
    float4 rec0A[2], rec1A[2];
    float  bcolA[2] = {0.0f, 0.0f};
    unsigned long long ktA[2] = {0, 0};

    #pragma unroll
    for (int half = 0; half < 2; ++half) {
        if (half == 1 && M <= TPB) continue;     // block-uniform
        const int t = half * TPB + tid;
        bool qp = false;
        if (t < M) {
            const int g = s_list[t];
            ktA[half] = s_ku[t];

            float4 q4 = ((const float4*)rot)[g];
            float qw = q4.x, qx = q4.y, qy = q4.z, qz = q4.w;
            float rn = __frsqrt_rn(qw*qw + qx*qx + qy*qy + qz*qz);
            qw *= rn; qx *= rn; qy *= rn; qz *= rn;
            float R00 = 1.f - 2.f*(qy*qy + qz*qz);
            float R01 = 2.f*(qx*qy - qw*qz);
            float R02 = 2.f*(qx*qz + qw*qy);
            float R10 = 2.f*(qx*qy + qw*qz);
            float R11 = 1.f - 2.f*(qx*qx + qz*qz);
            float R12 = 2.f*(qy*qz - qw*qx);
            float R20 = 2.f*(qx*qz - qw*qy);
            float R21 = 2.f*(qy*qz + qw*qx);
            float R22 = 1.f - 2.f*(qx*qx + qy*qy);

            float s0 = scl[g*3+0], s1 = scl[g*3+1], s2 = scl[g*3+2];
            float q0 = s0*s0, q1 = s1*s1, q2 = s2*s2;
            float C00 = R00*R00*q0 + R01*R01*q1 + R02*R02*q2;
            float C01 = R00*R10*q0 + R01*R11*q1 + R02*R12*q2;
            float C02 = R00*R20*q0 + R01*R21*q1 + R02*R22*q2;
            float C11 = R10*R10*q0 + R11*R11*q1 + R12*R12*q2;
            float C12 = R10*R20*q0 + R11*R21*q1 + R12*R22*q2;
            float C22 = R20*R20*q0 + R21*R21*q1 + R22*R22*q2;

            float px = pos[g*3+0], py = pos[g*3+1], pz = pos[g*3+2];
            float X = W00*px + W01*py + W02*pz + t0;
            float Y = W10*px + W11*py + W12*pz + t1;
            float Z = W20*px + W21*py + W22*pz + t2;

            float zs = fmaxf(Z, NEAR_P);
            float rz = __fdividef(1.0f, zs);
            float fxrz = fx * rz;

            float mx = fxrz * X + (float)IMG_W * 0.5f;
            float my = (float)IMG_H * 0.5f - fxrz * Y;

            float j02 = -fxrz * X * rz;
            float j12 = -fxrz * Y * rz;
            float T00 = fxrz*W00 + j02*W20;
            float T01 = fxrz*W01 + j02*W21;
            float T02 = fxrz*W02 + j02*W22;
            float T10 = fxrz*W10 + j12*W20;
            float T11 = fxrz*W11 + j12*W21;
            float T12 = fxrz*W12 + j12*W22;

            float u0 = C00*T00 + C01*T01 + C02*T02;
            float u1 = C01*T00 + C11*T01 + C12*T02;
            float u2 = C02*T00 + C12*T01 + C22*T02;
            float v0 = C00*T10 + C01*T11 + C02*T12;
            float v1 = C01*T10 + C11*T11 + C12*T12;
            float v2 = C02*T10 + C12*T11 + C22*T12;
            float a    = T00*u0 + T01*u1 + T02*u2;
            float bcov = 0.5f * ((T00*v0 + T01*v1 + T02*v2) + (T10*u0 + T11*u1 + T12*u2));
            float c    = T10*v0 + T11*v1 + T12*v2;

            float mean_e = 0.5f * (a + c);
            float disc = sqrtf(fmaxf(0.25f*(a - c)*(a - c) + bcov*bcov, 0.0f));
            float min_eig = mean_e - disc;
            float eps = (min_eig <= 0.0f) ? (fabsf(min_eig) + 1e-6f) : 0.0f;
            a += eps; c += eps;

            float det  = fmaxf(a*c - bcov*bcov, 1e-12f);
            float rdet = __fdividef(1.0f, det);
            float ca = c * rdet, cbv = -bcov * rdet, cc = a * rdet;
            float op = __fdividef(1.0f, 1.0f + __expf(-opa[g]));

            // exact ellipse bbox: min Mahalanobis to strip >= K outside
            float ex = CULL_K * sqrtf(fmaxf(a, 0.0f));
            float ey = CULL_K * sqrtf(fmaxf(c, 0.0f));
            qp = (fabsf(my - yf) <= ey) &
                 (mx >= x0f - ex) & (mx <= x0f + 63.0f + ex);

            rec0A[half] = make_float4(-0.5f*ca, -cbv, -0.5f*cc, mx);
            rec1A[half] = make_float4(my, op, col[g*3+0], col[g*3+1]);
            bcolA[half] = col[g*3+2];

            if (!qp) s_ku[t] = ~0ull;   // sentinel: excluded from ranks
        }
        unsigned long long mq = __ballot(qp);
        if (lane == 0) atomicAdd(&s_Mf, __popcll(mq));
        qpA[half] = qp;
    }
    __syncthreads();                                             // B5

    // ------- P3: rank among exact survivors + depth-ordered scatter -------
    #pragma unroll
    for (int half = 0; half < 2; ++half) {
        if (half == 1 && M <= TPB) continue;
        const int t = half * TPB + tid;
        if (t < M && qpA[half]) {
            const unsigned long long kt = ktA[half];
            const ulonglong2* ku2 = (const ulonglong2*)s_ku;
            int r = 0;
            const int M2 = (M + 1) >> 1;
            for (int j = 0; j < M2; ++j) {
                ulonglong2 kv = ku2[j];
                r += (int)(kv.x < kt);
                r += (int)(kv.y < kt);
            }
            s_cr0[r]  = rec0A[half];
            s_rec1[r] = rec1A[half];
            s_bcol[r] = bcolA[half];
        }
    }
    __syncthreads();                                             // B6

    // ---------------- P5: chunked composite -------------------------------
    const int Mf = s_Mf;
    const int qn = (Mf + CHUNKS - 1) / CHUNKS;
    const int lpix  = tid & 63;
    const int chunk = tid >> 6;
    int start = chunk * qn; if (start > Mf) start = Mf;
    int end   = start + qn; if (end > Mf) end = Mf;

    const float fxp = x0f + (float)lpix;

    float Tr = 1.0f, ar = 0.0f, ag = 0.0f, abv = 0.0f;
    for (int i = start; i < end; ++i) {
        float4 r0 = s_cr0[i];
        float4 r1 = s_rec1[i];
        float  bc = s_bcol[i];
        float dx = fxp - r0.w;
        float dy = yf  - r1.x;
        float qv = (r0.x*dx)*dx + (r0.y*dx)*dy + (r0.z*dy)*dy;  // = -0.5*q
        float G = __expf(fminf(qv, 0.0f));
        float alpha = fminf(r1.y * G, ALPHA_MAX);
        float wgt = alpha * Tr;
        ar  += wgt * r1.z;
        ag  += wgt * r1.w;
        abv += wgt * bc;
        Tr  *= (1.0f - alpha);
    }
    s_part[chunk][lpix] = make_float4(ar, ag, abv, Tr);
    __syncthreads();                                             // B7

    if (chunk == 0) {
        float4 c0 = s_part[0][lpix], c1 = s_part[1][lpix];
        float4 c2 = s_part[2][lpix], c3 = s_part[3][lpix];
        float T0 = c0.w, T01 = T0*c1.w, T012 = T01*c2.w, Tall = T012*c3.w;
        float r  = c0.x + T0*c1.x + T01*c2.x + T012*c3.x;
        float gc = c0.y + T0*c1.y + T01*c2.y + T012*c3.y;
        float bb = c0.z + T0*c1.z + T01*c2.z + T012*c3.z;
        float* o = out + (b * PIX + lpix) * 3;
        o[0] = r  + Tall * bg[0];
        o[1] = gc + Tall * bg[1];
        o[2] = bb + Tall * bg[2];
    }
}

extern "C" void kernel_launch(void* const* d_in, const int* in_sizes, int n_in,
                              void* d_out, int out_size, void* d_ws, size_t ws_size,
                              hipStream_t stream) {
    const float* pos = (const float*)d_in[0];
    const float* scl = (const float*)d_in[1];
    const float* rot = (const float*)d_in[2];
    const float* opa = (const float*)d_in[3];
    const float* col = (const float*)d_in[4];
    const float* vm  = (const float*)d_in[5];
    const float* bgp = (const float*)d_in[6];
    const int*   fov = (const int*)d_in[7];

    float* out = (float*)d_out;

    gs_fused<<<(IMG_H * IMG_W) / PIX, TPB, 0, stream>>>(
        pos, scl, rot, opa, col, vm, fov, bgp, out);
}